// Round 5
// baseline (234.238 us; speedup 1.0000x reference)
//
#include <hip/hip_runtime.h>
#include <hip/hip_bf16.h>

#define NN 100000
#define NE 3200000
#define NPB 64        // dst nodes per bucket
#define NB 1564       // 1564*64 = 100096 >= NN
#define CAP 2560      // mean 2046, sigma ~45 -> +11 sigma headroom
#define BATCH 8192    // edges staged per bin_k block

typedef __hip_bfloat16 bf16;

__device__ __forceinline__ void fma4(float4& a, float s, const float4 w) {
  a.x = fmaf(s, w.x, a.x);
  a.y = fmaf(s, w.y, a.y);
  a.z = fmaf(s, w.z, a.z);
  a.w = fmaf(s, w.w, a.w);
}

__device__ __forceinline__ unsigned short f2b(float f) {  // f32 -> bf16 RNE
  unsigned u = __float_as_uint(f);
  unsigned r = ((u >> 16) & 1u) + 0x7FFFu;
  return (unsigned short)((u + r) >> 16);
}

__device__ __forceinline__ unsigned pack2(float lo, float hi) {
  return (unsigned)f2b(lo) | ((unsigned)f2b(hi) << 16);
}

// Detect whether edge_index is int64 (high dwords of first 64 values all zero) or int32.
__global__ void detect_k(const int* __restrict__ e, int* __restrict__ flag) {
  unsigned long long b = __ballot(e[2 * (int)threadIdx.x + 1] == 0);
  if (threadIdx.x == 0) flag[0] = (b == 0xFFFFFFFFFFFFFFFFULL) ? 1 : 0;
}

// Binning: LDS histogram -> bulk range reservation (1 global atomic per
// block*bucket) -> direct scatter via LDS cursors.
__global__ __launch_bounds__(1024) void bin_k(const void* __restrict__ eidx,
                                              const int* __restrict__ flag,
                                              int* __restrict__ bcur,
                                              int* __restrict__ buckets) {
  __shared__ int scnt[NB];
  __shared__ int lcur[NB];
  int t = threadIdx.x;
  long long e0 = (long long)blockIdx.x * BATCH;
  int m = (int)((NE - e0 < BATCH) ? (NE - e0) : BATCH);
  int isI64 = flag[0];

  for (int i = t; i < NB; i += 1024) scnt[i] = 0;
  __syncthreads();

  int ent[BATCH / 1024], bv[BATCH / 1024];
#pragma unroll
  for (int j = 0; j < BATCH / 1024; j++) {
    int idx = t + j * 1024;
    bv[j] = -1;
    if (idx < m) {
      long long i = e0 + idx;
      int s, d;
      if (isI64) {
        s = (int)((const long long*)eidx)[i];
        d = (int)((const long long*)eidx)[NE + i];
      } else {
        s = ((const int*)eidx)[i];
        d = ((const int*)eidx)[NE + i];
      }
      bv[j] = d >> 6;
      ent[j] = s | ((d & 63) << 17);
      atomicAdd(&scnt[bv[j]], 1);
    }
  }
  __syncthreads();
  for (int i = t; i < NB; i += 1024) {
    int c = scnt[i];
    lcur[i] = c ? atomicAdd(&bcur[i], c) : 0;
  }
  __syncthreads();
#pragma unroll
  for (int j = 0; j < BATCH / 1024; j++) {
    if (bv[j] >= 0) {
      int pos = atomicAdd(&lcur[bv[j]], 1);
      if (pos < CAP) buckets[(size_t)bv[j] * CAP + pos] = ent[j];
    }
  }
}

// Per-bucket LDS histogram -> dinv + exact neighbor counts.
__global__ __launch_bounds__(256) void cnt_k(const int* __restrict__ buckets,
                                             const int* __restrict__ bcur,
                                             float* __restrict__ dinv,
                                             int* __restrict__ counts) {
  __shared__ int cnt[NPB];
  int b = blockIdx.x, t = threadIdx.x;
  if (t < NPB) cnt[t] = 0;
  __syncthreads();
  int m = bcur[b]; if (m > CAP) m = CAP;
  const int* bp = buckets + (size_t)b * CAP;
  for (int i = t; i < m; i += 256) atomicAdd(&cnt[(bp[i] >> 17) & 63], 1);
  __syncthreads();
  int node = b * NPB + t;
  if (t < NPB && node < NN) {
    dinv[node] = rsqrtf((float)cnt[t] + 1.0f);
    counts[node] = cnt[t];
  }
}

// h' = (x @ W_gcn) * dinv[row], bf16 out.
// v8: thread owns 8 rows x 4 cols (acc = 32 VGPR). NO LDS: W (64KB) is read
// directly from global per k-quad (4 float4 loads, coalesced across the 16
// fg-lanes, L2-resident after first touch) with 1-chunk prefetch, same as x.
// Occupancy is VGPR-bound (~145 -> 3 waves/SIMD = 12 waves/CU), 1.5x the LDS
// -limited v7; per-chunk cover ~296cy x 3 waves ~ 890cy vs ~900cy latency.
// x addressed from one advancing float4* (rows contiguous; NN%8==0 so each
// row-octet is all-valid or all-invalid -> clamp base, mask stores).
__global__ __launch_bounds__(256, 3) void gemm_k(const float* __restrict__ x,
                                                 const float* __restrict__ W,
                                                 const float* __restrict__ dinv,
                                                 bf16* __restrict__ h) {
  int t = threadIdx.x;
  int fg = t & 15;        // col group: cols fg*4 .. fg*4+3
  int rq = t >> 4;        // row octet [0,16)
  int row0 = blockIdx.x * 128 + rq * 8;       // rows row0 .. row0+7
  int row0c = row0 <= (NN - 8) ? row0 : (NN - 8);  // clamp loads, mask stores

  const float4* xp = (const float4*)(x + (size_t)row0c * 256);  // +1 per chunk
  const float4* wp = (const float4*)W + fg;                      // +64 per chunk

  float4 acc0 = make_float4(0.f, 0.f, 0.f, 0.f), acc1 = acc0, acc2 = acc0,
         acc3 = acc0, acc4 = acc0, acc5 = acc0, acc6 = acc0, acc7 = acc0;

  // chunk = one float4 (4 k-values) per row; row stride = 64 float4s
#define LOADX(N, P)                                                      \
  {                                                                      \
    N##_0 = P[0 * 64]; N##_1 = P[1 * 64]; N##_2 = P[2 * 64]; N##_3 = P[3 * 64]; \
    N##_4 = P[4 * 64]; N##_5 = P[5 * 64]; N##_6 = P[6 * 64]; N##_7 = P[7 * 64]; \
  }
#define LOADW(M, P)                                                      \
  {                                                                      \
    M##_0 = P[0]; M##_1 = P[16]; M##_2 = P[32]; M##_3 = P[48];           \
  }
#define WCOMP(N, M)                                                                                     \
  {                                                                                                     \
    fma4(acc0, N##_0.x, M##_0); fma4(acc0, N##_0.y, M##_1); fma4(acc0, N##_0.z, M##_2); fma4(acc0, N##_0.w, M##_3); \
    fma4(acc1, N##_1.x, M##_0); fma4(acc1, N##_1.y, M##_1); fma4(acc1, N##_1.z, M##_2); fma4(acc1, N##_1.w, M##_3); \
    fma4(acc2, N##_2.x, M##_0); fma4(acc2, N##_2.y, M##_1); fma4(acc2, N##_2.z, M##_2); fma4(acc2, N##_2.w, M##_3); \
    fma4(acc3, N##_3.x, M##_0); fma4(acc3, N##_3.y, M##_1); fma4(acc3, N##_3.z, M##_2); fma4(acc3, N##_3.w, M##_3); \
    fma4(acc4, N##_4.x, M##_0); fma4(acc4, N##_4.y, M##_1); fma4(acc4, N##_4.z, M##_2); fma4(acc4, N##_4.w, M##_3); \
    fma4(acc5, N##_5.x, M##_0); fma4(acc5, N##_5.y, M##_1); fma4(acc5, N##_5.z, M##_2); fma4(acc5, N##_5.w, M##_3); \
    fma4(acc6, N##_6.x, M##_0); fma4(acc6, N##_6.y, M##_1); fma4(acc6, N##_6.z, M##_2); fma4(acc6, N##_6.w, M##_3); \
    fma4(acc7, N##_7.x, M##_0); fma4(acc7, N##_7.y, M##_1); fma4(acc7, N##_7.z, M##_2); fma4(acc7, N##_7.w, M##_3); \
  }

  float4 xa_0, xa_1, xa_2, xa_3, xa_4, xa_5, xa_6, xa_7;
  float4 xb_0, xb_1, xb_2, xb_3, xb_4, xb_5, xb_6, xb_7;
  float4 wa_0, wa_1, wa_2, wa_3;
  float4 wb_0, wb_1, wb_2, wb_3;

  LOADX(xa, xp); xp += 1;
  LOADW(wa, wp); wp += 64;
#pragma unroll 1
  for (int ku = 0; ku < 31; ku++) {
    LOADX(xb, xp); xp += 1;
    LOADW(wb, wp); wp += 64;
    WCOMP(xa, wa);                 // chunk 2ku
    LOADX(xa, xp); xp += 1;
    LOADW(wa, wp); wp += 64;
    WCOMP(xb, wb);                 // chunk 2ku+1
    __builtin_amdgcn_sched_barrier(0);
  }
  LOADX(xb, xp);
  LOADW(wb, wp);
  WCOMP(xa, wa);                   // chunk 62
  WCOMP(xb, wb);                   // chunk 63
#undef LOADX
#undef LOADW
#undef WCOMP

  // epilogue: row i -> h[row][fg*4 .. fg*4+3] (8 B store per row)
#define STORE(I, A)                                                  \
  {                                                                  \
    int row = row0 + (I);                                            \
    if (row < NN) {                                                  \
      float dn = dinv[row];                                          \
      uint2 v;                                                       \
      v.x = pack2(A.x * dn, A.y * dn);                               \
      v.y = pack2(A.z * dn, A.w * dn);                               \
      *(uint2*)((unsigned short*)h + (size_t)row * 64 + fg * 4) = v; \
    }                                                                \
  }
  STORE(0, acc0); STORE(1, acc1); STORE(2, acc2); STORE(3, acc3);
  STORE(4, acc4); STORE(5, acc5); STORE(6, acc6); STORE(7, acc7);
#undef STORE
}

// Direct-accumulate aggregate v3: one block per 64-node bucket, 512 threads.
// Fixed-point (scale 2^15, bias 2^20 per 32-bit word) packed 2 feats per u64;
// native ds_add_u64 atomics (2 per edge). Entries staged in LDS; gather loop
// has no loop-carried deps -> deep pipelining.
__global__ __launch_bounds__(512) void agg_k(const bf16* __restrict__ h,
                                             const int* __restrict__ buckets,
                                             const int* __restrict__ bcur,
                                             const int* __restrict__ counts,
                                             const float* __restrict__ dinv,
                                             const float* __restrict__ bg,
                                             bf16* __restrict__ hg) {
  __shared__ unsigned long long acc[NPB * 33];  // 64 nodes x 32 pairs, stride 33
  __shared__ int ents[CAP];
  int b = blockIdx.x, t = threadIdx.x;
  int node0 = b * NPB;
  int m = bcur[b]; if (m > CAP) m = CAP;
  const int* bp = buckets + (size_t)b * CAP;
  for (int i = t; i < NPB * 33; i += 512) acc[i] = 0ULL;
  for (int i = t; i < m; i += 512) ents[i] = bp[i];
  __syncthreads();
  int w = t >> 6, lane = t & 63;
  int g = lane >> 4, fl = lane & 15;
  const unsigned short* hu = (const unsigned short*)h;
#pragma unroll 4
  for (int p = w * 4 + g; p < m; p += 32) {
    int e = ents[p];
    int src = e & 0x1FFFF;
    int dl = (e >> 17) & 63;
    uint2 v = *(const uint2*)(hu + (size_t)src * 64 + fl * 4);
    // bf16 -> f32 -> biased fixed point (all positive; round via +0.5 & trunc)
    unsigned i0 = (unsigned)fmaf(__uint_as_float(v.x << 16),          32768.f, 1048576.5f);
    unsigned i1 = (unsigned)fmaf(__uint_as_float(v.x & 0xFFFF0000u),  32768.f, 1048576.5f);
    unsigned i2 = (unsigned)fmaf(__uint_as_float(v.y << 16),          32768.f, 1048576.5f);
    unsigned i3 = (unsigned)fmaf(__uint_as_float(v.y & 0xFFFF0000u),  32768.f, 1048576.5f);
    unsigned long long u0 = (unsigned long long)i0 | ((unsigned long long)i1 << 32);
    unsigned long long u1 = (unsigned long long)i2 | ((unsigned long long)i3 << 32);
    unsigned long long* ap = acc + dl * 33 + fl * 2;
    atomicAdd(ap, u0);      // ds_add_u64, no return
    atomicAdd(ap + 1, u1);
  }
  __syncthreads();
  // epilogue: thread t -> node t>>3, feats (t&7)*8 .. +7
  int n = t >> 3, f0 = (t & 7) * 8;
  int node = node0 + n;
  if (node < NN) {
    int cnt = counts[node];
    unsigned bias32 = (unsigned)cnt << 20;
    float dn = dinv[node];
    const unsigned long long* ap = acc + n * 33 + (f0 >> 1);
    uint4 sv = *(const uint4*)(hu + (size_t)node * 64 + f0);   // self row, 8 bf16
    unsigned uu[4] = {sv.x, sv.y, sv.z, sv.w};
    const float* bb = bg + f0;
    unsigned short o[8];
#pragma unroll
    for (int j = 0; j < 4; j++) {
      unsigned long long u = ap[j];
      float vlo = (float)(int)((unsigned)u - bias32) * (1.f / 32768.f);
      float vhi = (float)(int)((unsigned)(u >> 32) - bias32) * (1.f / 32768.f);
      float slo = __uint_as_float(uu[j] << 16);
      float shi = __uint_as_float(uu[j] & 0xFFFF0000u);
      o[2 * j]     = f2b(fmaxf(fmaf(vlo + slo, dn, bb[2 * j]), 0.f));
      o[2 * j + 1] = f2b(fmaxf(fmaf(vhi + shi, dn, bb[2 * j + 1]), 0.f));
    }
    *(uint4*)((unsigned short*)hg + (size_t)node * 64 + f0) = *(uint4*)o;
  }
}

// Per-thread node MLP: 64 -> 32 -> 16 -> 4 + log_softmax.
__global__ __launch_bounds__(256) void mlp_k(const bf16* __restrict__ hg,
                                             const float* __restrict__ W1, const float* __restrict__ b1,
                                             const float* __restrict__ W2, const float* __restrict__ b2,
                                             const float* __restrict__ W3, const float* __restrict__ b3,
                                             float* __restrict__ out) {
  __shared__ float4 sW1[512];
  __shared__ float4 sW2[128];
  __shared__ float4 sW3[16];
  __shared__ float sb1[32], sb2[16], sb3[4];
  int t = threadIdx.x;
  for (int i = t; i < 512; i += 256) sW1[i] = ((const float4*)W1)[i];
  if (t < 128) sW2[t] = ((const float4*)W2)[t];
  if (t < 16)  sW3[t] = ((const float4*)W3)[t];
  if (t < 32)  sb1[t] = b1[t];
  if (t < 16)  sb2[t] = b2[t];
  if (t < 4)   sb3[t] = b3[t];
  __syncthreads();
  int n = blockIdx.x * 256 + t;
  if (n >= NN) return;
  float xr[64];
  const uint4* hp = (const uint4*)(hg + (size_t)n * 64);
#pragma unroll
  for (int i = 0; i < 8; i++) {
    uint4 v = hp[i];
    unsigned uu[4] = {v.x, v.y, v.z, v.w};
#pragma unroll
    for (int j = 0; j < 4; j++) {
      xr[8 * i + 2 * j]     = __uint_as_float(uu[j] << 16);
      xr[8 * i + 2 * j + 1] = __uint_as_float(uu[j] & 0xFFFF0000u);
    }
  }
  float4 a1[8];
#pragma unroll
  for (int j = 0; j < 8; j++) a1[j] = make_float4(sb1[4 * j], sb1[4 * j + 1], sb1[4 * j + 2], sb1[4 * j + 3]);
#pragma unroll
  for (int f = 0; f < 64; f++) {
    float xv = xr[f];
#pragma unroll
    for (int j = 0; j < 8; j++) fma4(a1[j], xv, sW1[f * 8 + j]);
  }
  float r2[32];
#pragma unroll
  for (int j = 0; j < 8; j++) {
    r2[4 * j + 0] = fmaxf(a1[j].x, 0.f);
    r2[4 * j + 1] = fmaxf(a1[j].y, 0.f);
    r2[4 * j + 2] = fmaxf(a1[j].z, 0.f);
    r2[4 * j + 3] = fmaxf(a1[j].w, 0.f);
  }
  float4 a2[4];
#pragma unroll
  for (int j = 0; j < 4; j++) a2[j] = make_float4(sb2[4 * j], sb2[4 * j + 1], sb2[4 * j + 2], sb2[4 * j + 3]);
#pragma unroll
  for (int f = 0; f < 32; f++) {
    float xv = r2[f];
#pragma unroll
    for (int j = 0; j < 4; j++) fma4(a2[j], xv, sW2[f * 4 + j]);
  }
  float r3[16];
#pragma unroll
  for (int j = 0; j < 4; j++) {
    r3[4 * j + 0] = fmaxf(a2[j].x, 0.f);
    r3[4 * j + 1] = fmaxf(a2[j].y, 0.f);
    r3[4 * j + 2] = fmaxf(a2[j].z, 0.f);
    r3[4 * j + 3] = fmaxf(a2[j].w, 0.f);
  }
  float4 a3 = make_float4(sb3[0], sb3[1], sb3[2], sb3[3]);
#pragma unroll
  for (int f = 0; f < 16; f++) fma4(a3, r3[f], sW3[f]);
  float m = fmaxf(fmaxf(a3.x, a3.y), fmaxf(a3.z, a3.w));
  float s = expf(a3.x - m) + expf(a3.y - m) + expf(a3.z - m) + expf(a3.w - m);
  float l = m + logf(s);
  ((float4*)out)[n] = make_float4(a3.x - l, a3.y - l, a3.z - l, a3.w - l);
}

extern "C" void kernel_launch(void* const* d_in, const int* in_sizes, int n_in,
                              void* d_out, int out_size, void* d_ws, size_t ws_size,
                              hipStream_t stream) {
  const float* x  = (const float*)d_in[0];
  const void* eidx = d_in[1];
  const float* Wg = (const float*)d_in[2];
  const float* bg = (const float*)d_in[3];
  const float* W1 = (const float*)d_in[4];
  const float* b1 = (const float*)d_in[5];
  const float* W2 = (const float*)d_in[6];
  const float* b2 = (const float*)d_in[7];
  const float* W3 = (const float*)d_in[8];
  const float* b3 = (const float*)d_in[9];

  char* ws = (char*)d_ws;
  bf16*  h       = (bf16*) (ws + 0);           // 12,800,000 B
  bf16*  hg      = (bf16*) (ws + 12800000);    // 12,800,000 B
  int*   buckets = (int*)  (ws + 25600000);    // 1564*2560*4 = 16,015,360 B
  float* dinv    = (float*)(ws + 41615360);    //    400,000 B
  int*   counts  = (int*)  (ws + 42015360);    //    400,000 B
  int*   bcur    = (int*)  (ws + 42415360);    //      6,256 B
  int*   flag    = (int*)  (ws + 42421632);

  detect_k<<<1, 64, 0, stream>>>((const int*)eidx, flag);
  hipMemsetAsync(bcur, 0, NB * sizeof(int), stream);
  bin_k<<<(NE + BATCH - 1) / BATCH, 1024, 0, stream>>>(eidx, flag, bcur, buckets);
  cnt_k<<<NB, 256, 0, stream>>>(buckets, bcur, dinv, counts);
  gemm_k<<<(NN + 127) / 128, 256, 0, stream>>>(x, Wg, dinv, h);
  agg_k<<<NB, 512, 0, stream>>>(h, buckets, bcur, counts, dinv, bg, hg);
  mlp_k<<<(NN + 255) / 256, 256, 0, stream>>>(hg, W1, b1, W2, b2, W3, b3, (float*)d_out);
}

// Round 6
// 171.065 us; speedup vs baseline: 1.3693x; 1.3693x over previous
//
#include <hip/hip_runtime.h>
#include <hip/hip_bf16.h>

#define NN 100000
#define NE 3200000
#define NPB 64        // dst nodes per bucket
#define NB 1564       // 1564*64 = 100096 >= NN
#define CAP 2560      // mean 2046, sigma ~45 -> +11 sigma headroom
#define BATCH 8192    // edges staged per bin_k block
#define NGB 1563      // gemm blocks: 1563*64 = 100032 >= NN

typedef __hip_bfloat16 bf16;
typedef __attribute__((ext_vector_type(8))) short bf16x8;  // 8 bf16 (4 VGPR)
typedef __attribute__((ext_vector_type(4))) float f32x4;

__device__ __forceinline__ void fma4(float4& a, float s, const float4 w) {
  a.x = fmaf(s, w.x, a.x);
  a.y = fmaf(s, w.y, a.y);
  a.z = fmaf(s, w.z, a.z);
  a.w = fmaf(s, w.w, a.w);
}

__device__ __forceinline__ unsigned short f2b(float f) {  // f32 -> bf16 RNE
  unsigned u = __float_as_uint(f);
  unsigned r = ((u >> 16) & 1u) + 0x7FFFu;
  return (unsigned short)((u + r) >> 16);
}

__device__ __forceinline__ unsigned pack2(float lo, float hi) {
  return (unsigned)f2b(lo) | ((unsigned)f2b(hi) << 16);
}

// Detect whether edge_index is int64 (high dwords of first 64 values all zero) or int32.
__global__ void detect_k(const int* __restrict__ e, int* __restrict__ flag) {
  unsigned long long b = __ballot(e[2 * (int)threadIdx.x + 1] == 0);
  if (threadIdx.x == 0) flag[0] = (b == 0xFFFFFFFFFFFFFFFFULL) ? 1 : 0;
}

// Binning: LDS histogram -> bulk range reservation (1 global atomic per
// block*bucket) -> direct scatter via LDS cursors.
__global__ __launch_bounds__(1024) void bin_k(const void* __restrict__ eidx,
                                              const int* __restrict__ flag,
                                              int* __restrict__ bcur,
                                              int* __restrict__ buckets) {
  __shared__ int scnt[NB];
  __shared__ int lcur[NB];
  int t = threadIdx.x;
  long long e0 = (long long)blockIdx.x * BATCH;
  int m = (int)((NE - e0 < BATCH) ? (NE - e0) : BATCH);
  int isI64 = flag[0];

  for (int i = t; i < NB; i += 1024) scnt[i] = 0;
  __syncthreads();

  int ent[BATCH / 1024], bv[BATCH / 1024];
#pragma unroll
  for (int j = 0; j < BATCH / 1024; j++) {
    int idx = t + j * 1024;
    bv[j] = -1;
    if (idx < m) {
      long long i = e0 + idx;
      int s, d;
      if (isI64) {
        s = (int)((const long long*)eidx)[i];
        d = (int)((const long long*)eidx)[NE + i];
      } else {
        s = ((const int*)eidx)[i];
        d = ((const int*)eidx)[NE + i];
      }
      bv[j] = d >> 6;
      ent[j] = s | ((d & 63) << 17);
      atomicAdd(&scnt[bv[j]], 1);
    }
  }
  __syncthreads();
  for (int i = t; i < NB; i += 1024) {
    int c = scnt[i];
    lcur[i] = c ? atomicAdd(&bcur[i], c) : 0;
  }
  __syncthreads();
#pragma unroll
  for (int j = 0; j < BATCH / 1024; j++) {
    if (bv[j] >= 0) {
      int pos = atomicAdd(&lcur[bv[j]], 1);
      if (pos < CAP) buckets[(size_t)bv[j] * CAP + pos] = ent[j];
    }
  }
}

// Per-bucket LDS histogram -> dinv + exact neighbor counts.
__global__ __launch_bounds__(256) void cnt_k(const int* __restrict__ buckets,
                                             const int* __restrict__ bcur,
                                             float* __restrict__ dinv,
                                             int* __restrict__ counts) {
  __shared__ int cnt[NPB];
  int b = blockIdx.x, t = threadIdx.x;
  if (t < NPB) cnt[t] = 0;
  __syncthreads();
  int m = bcur[b]; if (m > CAP) m = CAP;
  const int* bp = buckets + (size_t)b * CAP;
  for (int i = t; i < m; i += 256) atomicAdd(&cnt[(bp[i] >> 17) & 63], 1);
  __syncthreads();
  int node = b * NPB + t;
  if (t < NPB && node < NN) {
    dinv[node] = rsqrtf((float)cnt[t] + 1.0f);
    counts[node] = cnt[t];
  }
}

// Convert W (256x64 f32) into MFMA-B-fragment-ordered bf16 hi/lo buffers.
// Element (kk,nf,lane,j): k = kk*32 + (lane>>4)*8 + j, n = nf*16 + (lane&15).
// Linear index = ((kk*4 + nf)*64 + lane)*8 + j.  wh = bf16 RNE of W,
// wl = bf16 RNE of (W - f32(wh))  ->  wh + wl == W to ~2^-18 rel.
__global__ __launch_bounds__(256) void prep_k(const float* __restrict__ W,
                                              unsigned short* __restrict__ wh,
                                              unsigned short* __restrict__ wl) {
  int t = threadIdx.x;
#pragma unroll 4
  for (int i = 0; i < 64; i++) {
    int idx = i * 256 + t;
    int j = idx & 7;
    int lane = (idx >> 3) & 63;
    int pair = idx >> 9;           // kk*4 + nf
    int nf = pair & 3, kk = pair >> 2;
    int k = kk * 32 + (lane >> 4) * 8 + j;
    int n = nf * 16 + (lane & 15);
    float w = W[k * 64 + n];
    unsigned short hh = f2b(w);
    float fh = __uint_as_float((unsigned)hh << 16);
    wh[idx] = hh;
    wl[idx] = f2b(w - fh);
  }
}

// h' = (x @ W_gcn) * dinv[row], bf16 out.
// v9 (MFMA): split-precision bf16 matrix cores. Per wave: 16 rows x 64 cols,
// K-loop 8 steps of 32. Each step: lane loads its 8 x-f32 (A-frag window,
// 16 rows x 128B contiguous per wave), splits to xh/xl bf16, loads 8
// fragment-ordered B vectors (coalesced 16B/lane, L2-resident 64KB), and
// issues 12 mfma_f32_16x16x32_bf16: acc += xh*Wh + xh*Wl + xl*Wh (f32 acc;
// error ~2^-17, numerically == f32). No LDS; grid 1563 -> ~24 waves/CU TLP
// hides x latency. C/D layout (m89-verified): col=lane&15, row=(l>>4)*4+reg.
__global__ __launch_bounds__(256) void gemm_k(const float* __restrict__ x,
                                              const unsigned short* __restrict__ wh,
                                              const unsigned short* __restrict__ wl,
                                              const float* __restrict__ dinv,
                                              bf16* __restrict__ h) {
  int t = threadIdx.x;
  int wv = t >> 6, l = t & 63;
  int rowbase = blockIdx.x * 64 + wv * 16;
  int arow = rowbase + (l & 15);
  if (arow >= NN) arow = NN - 1;           // clamp loads, mask stores
  const float* xrow = x + (size_t)arow * 256 + (l >> 4) * 8;

  const bf16x8* whf = (const bf16x8*)wh;   // [ (kk*4+nf)*64 + lane ]
  const bf16x8* wlf = (const bf16x8*)wl;

  f32x4 acc0 = {0.f, 0.f, 0.f, 0.f};
  f32x4 acc1 = acc0, acc2 = acc0, acc3 = acc0;

#pragma unroll 1
  for (int kk = 0; kk < 8; kk++) {
    float4 xv0 = *(const float4*)(xrow + kk * 32);
    float4 xv1 = *(const float4*)(xrow + kk * 32 + 4);
    bf16x8 ah, al;
#define SP(J, F)                                                   \
    {                                                              \
      unsigned short hh_ = f2b(F);                                 \
      float fh_ = __uint_as_float((unsigned)hh_ << 16);            \
      ah[J] = (short)hh_;                                          \
      al[J] = (short)f2b((F) - fh_);                               \
    }
    SP(0, xv0.x) SP(1, xv0.y) SP(2, xv0.z) SP(3, xv0.w)
    SP(4, xv1.x) SP(5, xv1.y) SP(6, xv1.z) SP(7, xv1.w)
#undef SP
    int fb = kk * 256 + l;
    bf16x8 bh0 = whf[fb], bh1 = whf[fb + 64], bh2 = whf[fb + 128], bh3 = whf[fb + 192];
    bf16x8 bl0 = wlf[fb], bl1 = wlf[fb + 64], bl2 = wlf[fb + 128], bl3 = wlf[fb + 192];
    acc0 = __builtin_amdgcn_mfma_f32_16x16x32_bf16(ah, bh0, acc0, 0, 0, 0);
    acc1 = __builtin_amdgcn_mfma_f32_16x16x32_bf16(ah, bh1, acc1, 0, 0, 0);
    acc2 = __builtin_amdgcn_mfma_f32_16x16x32_bf16(ah, bh2, acc2, 0, 0, 0);
    acc3 = __builtin_amdgcn_mfma_f32_16x16x32_bf16(ah, bh3, acc3, 0, 0, 0);
    acc0 = __builtin_amdgcn_mfma_f32_16x16x32_bf16(ah, bl0, acc0, 0, 0, 0);
    acc1 = __builtin_amdgcn_mfma_f32_16x16x32_bf16(ah, bl1, acc1, 0, 0, 0);
    acc2 = __builtin_amdgcn_mfma_f32_16x16x32_bf16(ah, bl2, acc2, 0, 0, 0);
    acc3 = __builtin_amdgcn_mfma_f32_16x16x32_bf16(ah, bl3, acc3, 0, 0, 0);
    acc0 = __builtin_amdgcn_mfma_f32_16x16x32_bf16(al, bh0, acc0, 0, 0, 0);
    acc1 = __builtin_amdgcn_mfma_f32_16x16x32_bf16(al, bh1, acc1, 0, 0, 0);
    acc2 = __builtin_amdgcn_mfma_f32_16x16x32_bf16(al, bh2, acc2, 0, 0, 0);
    acc3 = __builtin_amdgcn_mfma_f32_16x16x32_bf16(al, bh3, acc3, 0, 0, 0);
  }

  // epilogue: lane stores rows (l>>4)*4+reg, cols nf*16 + (l&15)
#pragma unroll
  for (int reg = 0; reg < 4; reg++) {
    int row = rowbase + (l >> 4) * 4 + reg;
    if (row < NN) {
      float dn = dinv[row];
      unsigned short* hp = (unsigned short*)h + (size_t)row * 64 + (l & 15);
      hp[0]  = f2b(acc0[reg] * dn);
      hp[16] = f2b(acc1[reg] * dn);
      hp[32] = f2b(acc2[reg] * dn);
      hp[48] = f2b(acc3[reg] * dn);
    }
  }
}

// Direct-accumulate aggregate v3: one block per 64-node bucket, 512 threads.
// Fixed-point (scale 2^15, bias 2^20 per 32-bit word) packed 2 feats per u64;
// native ds_add_u64 atomics (2 per edge). Entries staged in LDS; gather loop
// has no loop-carried deps -> deep pipelining.
__global__ __launch_bounds__(512) void agg_k(const bf16* __restrict__ h,
                                             const int* __restrict__ buckets,
                                             const int* __restrict__ bcur,
                                             const int* __restrict__ counts,
                                             const float* __restrict__ dinv,
                                             const float* __restrict__ bg,
                                             bf16* __restrict__ hg) {
  __shared__ unsigned long long acc[NPB * 33];  // 64 nodes x 32 pairs, stride 33
  __shared__ int ents[CAP];
  int b = blockIdx.x, t = threadIdx.x;
  int node0 = b * NPB;
  int m = bcur[b]; if (m > CAP) m = CAP;
  const int* bp = buckets + (size_t)b * CAP;
  for (int i = t; i < NPB * 33; i += 512) acc[i] = 0ULL;
  for (int i = t; i < m; i += 512) ents[i] = bp[i];
  __syncthreads();
  int w = t >> 6, lane = t & 63;
  int g = lane >> 4, fl = lane & 15;
  const unsigned short* hu = (const unsigned short*)h;
#pragma unroll 4
  for (int p = w * 4 + g; p < m; p += 32) {
    int e = ents[p];
    int src = e & 0x1FFFF;
    int dl = (e >> 17) & 63;
    uint2 v = *(const uint2*)(hu + (size_t)src * 64 + fl * 4);
    // bf16 -> f32 -> biased fixed point (all positive; round via +0.5 & trunc)
    unsigned i0 = (unsigned)fmaf(__uint_as_float(v.x << 16),          32768.f, 1048576.5f);
    unsigned i1 = (unsigned)fmaf(__uint_as_float(v.x & 0xFFFF0000u),  32768.f, 1048576.5f);
    unsigned i2 = (unsigned)fmaf(__uint_as_float(v.y << 16),          32768.f, 1048576.5f);
    unsigned i3 = (unsigned)fmaf(__uint_as_float(v.y & 0xFFFF0000u),  32768.f, 1048576.5f);
    unsigned long long u0 = (unsigned long long)i0 | ((unsigned long long)i1 << 32);
    unsigned long long u1 = (unsigned long long)i2 | ((unsigned long long)i3 << 32);
    unsigned long long* ap = acc + dl * 33 + fl * 2;
    atomicAdd(ap, u0);      // ds_add_u64, no return
    atomicAdd(ap + 1, u1);
  }
  __syncthreads();
  // epilogue: thread t -> node t>>3, feats (t&7)*8 .. +7
  int n = t >> 3, f0 = (t & 7) * 8;
  int node = node0 + n;
  if (node < NN) {
    int cnt = counts[node];
    unsigned bias32 = (unsigned)cnt << 20;
    float dn = dinv[node];
    const unsigned long long* ap = acc + n * 33 + (f0 >> 1);
    uint4 sv = *(const uint4*)(hu + (size_t)node * 64 + f0);   // self row, 8 bf16
    unsigned uu[4] = {sv.x, sv.y, sv.z, sv.w};
    const float* bb = bg + f0;
    unsigned short o[8];
#pragma unroll
    for (int j = 0; j < 4; j++) {
      unsigned long long u = ap[j];
      float vlo = (float)(int)((unsigned)u - bias32) * (1.f / 32768.f);
      float vhi = (float)(int)((unsigned)(u >> 32) - bias32) * (1.f / 32768.f);
      float slo = __uint_as_float(uu[j] << 16);
      float shi = __uint_as_float(uu[j] & 0xFFFF0000u);
      o[2 * j]     = f2b(fmaxf(fmaf(vlo + slo, dn, bb[2 * j]), 0.f));
      o[2 * j + 1] = f2b(fmaxf(fmaf(vhi + shi, dn, bb[2 * j + 1]), 0.f));
    }
    *(uint4*)((unsigned short*)hg + (size_t)node * 64 + f0) = *(uint4*)o;
  }
}

// Per-thread node MLP: 64 -> 32 -> 16 -> 4 + log_softmax.
__global__ __launch_bounds__(256) void mlp_k(const bf16* __restrict__ hg,
                                             const float* __restrict__ W1, const float* __restrict__ b1,
                                             const float* __restrict__ W2, const float* __restrict__ b2,
                                             const float* __restrict__ W3, const float* __restrict__ b3,
                                             float* __restrict__ out) {
  __shared__ float4 sW1[512];
  __shared__ float4 sW2[128];
  __shared__ float4 sW3[16];
  __shared__ float sb1[32], sb2[16], sb3[4];
  int t = threadIdx.x;
  for (int i = t; i < 512; i += 256) sW1[i] = ((const float4*)W1)[i];
  if (t < 128) sW2[t] = ((const float4*)W2)[t];
  if (t < 16)  sW3[t] = ((const float4*)W3)[t];
  if (t < 32)  sb1[t] = b1[t];
  if (t < 16)  sb2[t] = b2[t];
  if (t < 4)   sb3[t] = b3[t];
  __syncthreads();
  int n = blockIdx.x * 256 + t;
  if (n >= NN) return;
  float xr[64];
  const uint4* hp = (const uint4*)(hg + (size_t)n * 64);
#pragma unroll
  for (int i = 0; i < 8; i++) {
    uint4 v = hp[i];
    unsigned uu[4] = {v.x, v.y, v.z, v.w};
#pragma unroll
    for (int j = 0; j < 4; j++) {
      xr[8 * i + 2 * j]     = __uint_as_float(uu[j] << 16);
      xr[8 * i + 2 * j + 1] = __uint_as_float(uu[j] & 0xFFFF0000u);
    }
  }
  float4 a1[8];
#pragma unroll
  for (int j = 0; j < 8; j++) a1[j] = make_float4(sb1[4 * j], sb1[4 * j + 1], sb1[4 * j + 2], sb1[4 * j + 3]);
#pragma unroll
  for (int f = 0; f < 64; f++) {
    float xv = xr[f];
#pragma unroll
    for (int j = 0; j < 8; j++) fma4(a1[j], xv, sW1[f * 8 + j]);
  }
  float r2[32];
#pragma unroll
  for (int j = 0; j < 8; j++) {
    r2[4 * j + 0] = fmaxf(a1[j].x, 0.f);
    r2[4 * j + 1] = fmaxf(a1[j].y, 0.f);
    r2[4 * j + 2] = fmaxf(a1[j].z, 0.f);
    r2[4 * j + 3] = fmaxf(a1[j].w, 0.f);
  }
  float4 a2[4];
#pragma unroll
  for (int j = 0; j < 4; j++) a2[j] = make_float4(sb2[4 * j], sb2[4 * j + 1], sb2[4 * j + 2], sb2[4 * j + 3]);
#pragma unroll
  for (int f = 0; f < 32; f++) {
    float xv = r2[f];
#pragma unroll
    for (int j = 0; j < 4; j++) fma4(a2[j], xv, sW2[f * 4 + j]);
  }
  float r3[16];
#pragma unroll
  for (int j = 0; j < 4; j++) {
    r3[4 * j + 0] = fmaxf(a2[j].x, 0.f);
    r3[4 * j + 1] = fmaxf(a2[j].y, 0.f);
    r3[4 * j + 2] = fmaxf(a2[j].z, 0.f);
    r3[4 * j + 3] = fmaxf(a2[j].w, 0.f);
  }
  float4 a3 = make_float4(sb3[0], sb3[1], sb3[2], sb3[3]);
#pragma unroll
  for (int f = 0; f < 16; f++) fma4(a3, r3[f], sW3[f]);
  float m = fmaxf(fmaxf(a3.x, a3.y), fmaxf(a3.z, a3.w));
  float s = expf(a3.x - m) + expf(a3.y - m) + expf(a3.z - m) + expf(a3.w - m);
  float l = m + logf(s);
  ((float4*)out)[n] = make_float4(a3.x - l, a3.y - l, a3.z - l, a3.w - l);
}

extern "C" void kernel_launch(void* const* d_in, const int* in_sizes, int n_in,
                              void* d_out, int out_size, void* d_ws, size_t ws_size,
                              hipStream_t stream) {
  const float* x  = (const float*)d_in[0];
  const void* eidx = d_in[1];
  const float* Wg = (const float*)d_in[2];
  const float* bg = (const float*)d_in[3];
  const float* W1 = (const float*)d_in[4];
  const float* b1 = (const float*)d_in[5];
  const float* W2 = (const float*)d_in[6];
  const float* b2 = (const float*)d_in[7];
  const float* W3 = (const float*)d_in[8];
  const float* b3 = (const float*)d_in[9];

  char* ws = (char*)d_ws;
  bf16*  h       = (bf16*) (ws + 0);           // 12,800,000 B
  bf16*  hg      = (bf16*) (ws + 12800000);    // 12,800,000 B
  int*   buckets = (int*)  (ws + 25600000);    // 1564*2560*4 = 16,015,360 B
  float* dinv    = (float*)(ws + 41615360);    //    400,000 B
  int*   counts  = (int*)  (ws + 42015360);    //    400,000 B
  int*   bcur    = (int*)  (ws + 42415360);    //      6,256 B
  int*   flag    = (int*)  (ws + 42421632);
  // wh/wl (32KB each) live in the hg region: hg is only WRITTEN by agg_k,
  // which runs after gemm_k has finished reading wh/wl (stream-ordered).
  unsigned short* wh = (unsigned short*)(ws + 12800000);
  unsigned short* wl = (unsigned short*)(ws + 12800000 + 32768);

  detect_k<<<1, 64, 0, stream>>>((const int*)eidx, flag);
  hipMemsetAsync(bcur, 0, NB * sizeof(int), stream);
  bin_k<<<(NE + BATCH - 1) / BATCH, 1024, 0, stream>>>(eidx, flag, bcur, buckets);
  cnt_k<<<NB, 256, 0, stream>>>(buckets, bcur, dinv, counts);
  prep_k<<<1, 256, 0, stream>>>(Wg, wh, wl);
  gemm_k<<<NGB, 256, 0, stream>>>(x, wh, wl, dinv, h);
  agg_k<<<NB, 512, 0, stream>>>(h, buckets, bcur, counts, dinv, bg, hg);
  mlp_k<<<(NN + 255) / 256, 256, 0, stream>>>(hg, W1, b1, W2, b2, W3, b3, (float*)d_out);
}